// Round 1
// baseline (864.698 us; speedup 1.0000x reference)
//
#include <hip/hip_runtime.h>
#include <cstdint>
#include <cstddef>

#define FEAT 512
#define HID 256
#define CLS 40
#define EPS 1e-5f

// ---------------- preprocessing: degree, CSR build ----------------

__global__ void zero_kernel(int* counts, int* fillpos, int n) {
    int i = blockIdx.x * 256 + threadIdx.x;
    if (i < n) { counts[i] = 0; fillpos[i] = 0; }
}

__global__ void hist_kernel(const int* __restrict__ dst, int* __restrict__ counts, int E) {
    int e = blockIdx.x * 256 + threadIdx.x;
    if (e < E) atomicAdd(&counts[dst[e]], 1);
}

// inclusive scan per 256-block; emits per-element exclusive (pre-offset) + block sums
__global__ void scan_block_kernel(const int* __restrict__ counts, int* __restrict__ row_ptr,
                                  int* __restrict__ blocksums, int n) {
    __shared__ int s[256];
    int tid = threadIdx.x;
    int i = blockIdx.x * 256 + tid;
    int v = (i < n) ? counts[i] : 0;
    s[tid] = v; __syncthreads();
    for (int off = 1; off < 256; off <<= 1) {
        int t = (tid >= off) ? s[tid - off] : 0;
        __syncthreads();
        s[tid] += t;
        __syncthreads();
    }
    if (i < n) row_ptr[i] = s[tid] - v;          // exclusive within block
    if (tid == 255) blocksums[blockIdx.x] = s[255];
}

__global__ void scan_sums_kernel(const int* __restrict__ blocksums, int* __restrict__ blockoffs, int nb) {
    __shared__ int s[256];
    int tid = threadIdx.x;
    int v = (tid < nb) ? blocksums[tid] : 0;
    s[tid] = v; __syncthreads();
    for (int off = 1; off < 256; off <<= 1) {
        int t = (tid >= off) ? s[tid - off] : 0;
        __syncthreads();
        s[tid] += t;
        __syncthreads();
    }
    blockoffs[tid] = s[tid] - v;                 // exclusive block offsets
}

__global__ void finalize_rowptr_kernel(int* __restrict__ row_ptr, const int* __restrict__ blockoffs,
                                       const int* __restrict__ counts, float* __restrict__ inv_sqrt,
                                       int n, int E) {
    int i = blockIdx.x * 256 + threadIdx.x;
    if (i < n) {
        row_ptr[i] += blockoffs[i >> 8];
        // deg = edge count + self-loop (always >= 1)
        inv_sqrt[i] = rsqrtf((float)(counts[i] + 1));
    }
    if (i == 0) row_ptr[n] = E;
}

__global__ void fill_kernel(const int* __restrict__ src, const int* __restrict__ dst,
                            const int* __restrict__ row_ptr, int* __restrict__ fillpos,
                            int* __restrict__ src_sorted, int E) {
    int e = blockIdx.x * 256 + threadIdx.x;
    if (e < E) {
        int d = dst[e];
        int pos = row_ptr[d] + atomicAdd(&fillpos[d], 1);
        src_sorted[pos] = src[e];
    }
}

// ---------------- GEMM: C[row] = (A @ W)[row] * inv_sqrt[row] ----------------
// 64x64 tile, BK=16, 256 threads, 4x4 micro-tile per thread. fp32 vector FMA.

__global__ __launch_bounds__(256) void gemm_scaled_kernel(
        const float* __restrict__ A, const float* __restrict__ W,
        const float* __restrict__ inv_sqrt, float* __restrict__ C,
        int M, int K, int Ncol) {
    __shared__ float As[16][64];   // [k][m]
    __shared__ float Ws[16][64];   // [k][n]
    int tid = threadIdx.x;
    int tm = tid >> 4;             // 0..15
    int tn = tid & 15;             // 0..15
    int bm = blockIdx.x * 64;
    int bn = blockIdx.y * 64;

    float acc[4][4] = {};

    int lr = tid >> 2;             // A-load row within tile 0..63
    int lc = (tid & 3) << 2;       // A-load col 0,4,8,12
    int wr = tid >> 4;             // W-load row 0..15
    int wc = (tid & 15) << 2;      // W-load col 0..60
    int arow = bm + lr;
    bool aok = arow < M;
    bool wok = (bn + wc) < Ncol;   // Ncol is a multiple of 4 (256 or 40)
    const float* Arow = A + (size_t)arow * K + lc;

    for (int k0 = 0; k0 < K; k0 += 16) {
        float4 av = make_float4(0.f, 0.f, 0.f, 0.f);
        if (aok) av = *(const float4*)(Arow + k0);
        As[lc + 0][lr] = av.x; As[lc + 1][lr] = av.y;
        As[lc + 2][lr] = av.z; As[lc + 3][lr] = av.w;

        float4 wv = make_float4(0.f, 0.f, 0.f, 0.f);
        if (wok) wv = *(const float4*)(W + (size_t)(k0 + wr) * Ncol + bn + wc);
        *(float4*)&Ws[wr][wc] = wv;
        __syncthreads();

#pragma unroll
        for (int k = 0; k < 16; ++k) {
            const float4 a4 = *(const float4*)&As[k][tm << 2];
            const float4 b4 = *(const float4*)&Ws[k][tn << 2];
            float a[4] = {a4.x, a4.y, a4.z, a4.w};
            float b[4] = {b4.x, b4.y, b4.z, b4.w};
#pragma unroll
            for (int i = 0; i < 4; ++i)
#pragma unroll
                for (int j = 0; j < 4; ++j)
                    acc[i][j] = fmaf(a[i], b[j], acc[i][j]);
        }
        __syncthreads();
    }

#pragma unroll
    for (int i = 0; i < 4; ++i) {
        int row = bm + (tm << 2) + i;
        if (row >= M) continue;
        float s = inv_sqrt[row];
        int col = bn + (tn << 2);
        if (col < Ncol) {
            float4 o = make_float4(acc[i][0] * s, acc[i][1] * s, acc[i][2] * s, acc[i][3] * s);
            *(float4*)&C[(size_t)row * Ncol + col] = o;
        }
    }
}

// ---------------- aggregation (H=256): one wave per node, float4 per lane ----------------
// out[i] = relu( ((self + sum_nbr g) * inv_sqrt[i] + bias - mean) * gamma*rsqrt(var+eps) + beta )

__global__ __launch_bounds__(256) void agg_bn_kernel(
        const float* __restrict__ g, const int* __restrict__ row_ptr,
        const int* __restrict__ srcs, const float* __restrict__ inv_sqrt,
        const float* __restrict__ bias, const float* __restrict__ gamma,
        const float* __restrict__ beta, const float* __restrict__ mean,
        const float* __restrict__ var, float* __restrict__ out, int n) {
    int node = (blockIdx.x << 2) + (threadIdx.x >> 6);
    int lane = threadIdx.x & 63;           // 64 lanes * float4 = 256 feats
    if (node >= n) return;
    const float4* gp = (const float4*)g;
    float4 acc = gp[(size_t)node * 64 + lane];   // self-loop term
    int beg = row_ptr[node], end = row_ptr[node + 1];
    for (int e = beg; e < end; ++e) {
        int s = srcs[e];
        float4 v = gp[(size_t)s * 64 + lane];
        acc.x += v.x; acc.y += v.y; acc.z += v.z; acc.w += v.w;
    }
    float inv = inv_sqrt[node];
    float4 b4  = ((const float4*)bias)[lane];
    float4 ga4 = ((const float4*)gamma)[lane];
    float4 be4 = ((const float4*)beta)[lane];
    float4 m4  = ((const float4*)mean)[lane];
    float4 v4  = ((const float4*)var)[lane];
    float sx = ga4.x * rsqrtf(v4.x + EPS);
    float sy = ga4.y * rsqrtf(v4.y + EPS);
    float sz = ga4.z * rsqrtf(v4.z + EPS);
    float sw = ga4.w * rsqrtf(v4.w + EPS);
    float4 o;
    o.x = fmaxf((acc.x * inv + b4.x - m4.x) * sx + be4.x, 0.f);
    o.y = fmaxf((acc.y * inv + b4.y - m4.y) * sy + be4.y, 0.f);
    o.z = fmaxf((acc.z * inv + b4.z - m4.z) * sz + be4.z, 0.f);
    o.w = fmaxf((acc.w * inv + b4.w - m4.w) * sw + be4.w, 0.f);
    ((float4*)out)[(size_t)node * 64 + lane] = o;
}

// ---------------- final aggregation (C=40): one wave per node, scalar per lane ----------------

__global__ __launch_bounds__(256) void agg_final_kernel(
        const float* __restrict__ g, const int* __restrict__ row_ptr,
        const int* __restrict__ srcs, const float* __restrict__ inv_sqrt,
        const float* __restrict__ bias, float* __restrict__ out, int n) {
    int node = (blockIdx.x << 2) + (threadIdx.x >> 6);
    int lane = threadIdx.x & 63;
    if (node >= n || lane >= CLS) return;
    float acc = g[(size_t)node * CLS + lane];    // self-loop
    int beg = row_ptr[node], end = row_ptr[node + 1];
    for (int e = beg; e < end; ++e)
        acc += g[(size_t)srcs[e] * CLS + lane];
    out[(size_t)node * CLS + lane] = acc * inv_sqrt[node] + bias[lane];
}

// ---------------- launch ----------------

extern "C" void kernel_launch(void* const* d_in, const int* in_sizes, int n_in,
                              void* d_out, int out_size, void* d_ws, size_t ws_size,
                              hipStream_t stream) {
    const float* x     = (const float*)d_in[0];
    const int*   edges = (const int*)d_in[1];
    const float* W1    = (const float*)d_in[2];
    const float* b1    = (const float*)d_in[3];
    const float* W2    = (const float*)d_in[4];
    const float* b2    = (const float*)d_in[5];
    const float* W3    = (const float*)d_in[6];
    const float* b3    = (const float*)d_in[7];
    const float* gamma = (const float*)d_in[8];
    const float* beta  = (const float*)d_in[9];
    const float* mean  = (const float*)d_in[10];
    const float* var   = (const float*)d_in[11];

    const int N = in_sizes[0] / FEAT;   // 50000
    const int E = in_sizes[1] / 2;      // 800000
    const int* src = edges;
    const int* dst = edges + E;

    char* ws = (char*)d_ws;
    auto alloc = [&](size_t bytes) -> char* {
        char* p = ws;
        ws += (bytes + 255) & ~(size_t)255;
        return p;
    };
    int*   counts     = (int*)  alloc((size_t)N * 4);
    int*   fillpos    = (int*)  alloc((size_t)N * 4);
    int*   row_ptr    = (int*)  alloc((size_t)(N + 1) * 4);
    int*   blocksums  = (int*)  alloc(256 * 4);
    int*   blockoffs  = (int*)  alloc(256 * 4);
    float* inv_sqrt   = (float*)alloc((size_t)N * 4);
    int*   src_sorted = (int*)  alloc((size_t)E * 4);
    float* bufA       = (float*)alloc((size_t)N * HID * 4);
    float* bufB       = (float*)alloc((size_t)N * HID * 4);
    float* bufC       = bufA;   // layer-3 GEMM output (N*CLS) reuses bufA

    int nb = (N + 255) / 256;   // 196 (<=256, fits single-block scan)
    int eb = (E + 255) / 256;

    zero_kernel<<<nb, 256, 0, stream>>>(counts, fillpos, N);
    hist_kernel<<<eb, 256, 0, stream>>>(dst, counts, E);
    scan_block_kernel<<<nb, 256, 0, stream>>>(counts, row_ptr, blocksums, N);
    scan_sums_kernel<<<1, 256, 0, stream>>>(blocksums, blockoffs, nb);
    finalize_rowptr_kernel<<<nb, 256, 0, stream>>>(row_ptr, blockoffs, counts, inv_sqrt, N, E);
    fill_kernel<<<eb, 256, 0, stream>>>(src, dst, row_ptr, fillpos, src_sorted, E);

    dim3 gemm_grid1((N + 63) / 64, HID / 64);
    dim3 gemm_grid3((N + 63) / 64, 1);
    dim3 agg_grid((N + 3) / 4);

    // layer 1
    gemm_scaled_kernel<<<gemm_grid1, 256, 0, stream>>>(x, W1, inv_sqrt, bufA, N, FEAT, HID);
    agg_bn_kernel<<<agg_grid, 256, 0, stream>>>(bufA, row_ptr, src_sorted, inv_sqrt,
                                                b1, gamma, beta, mean, var, bufB, N);
    // layer 2
    gemm_scaled_kernel<<<gemm_grid1, 256, 0, stream>>>(bufB, W2, inv_sqrt, bufA, N, HID, HID);
    agg_bn_kernel<<<agg_grid, 256, 0, stream>>>(bufA, row_ptr, src_sorted, inv_sqrt,
                                                b2, gamma, beta, mean, var, bufB, N);
    // layer 3
    gemm_scaled_kernel<<<gemm_grid3, 256, 0, stream>>>(bufB, W3, inv_sqrt, bufC, N, HID, CLS);
    agg_final_kernel<<<agg_grid, 256, 0, stream>>>(bufC, row_ptr, src_sorted, inv_sqrt,
                                                   b3, (float*)d_out, N);
}

// Round 3
// 713.298 us; speedup vs baseline: 1.2123x; 1.2123x over previous
//
#include <hip/hip_runtime.h>
#include <cstdint>
#include <cstddef>

#define FEAT 512
#define HID 256
#define CLS 40
#define EPS 1e-5f

typedef __attribute__((ext_vector_type(8))) short short8;
typedef __attribute__((ext_vector_type(4))) float f32x4v;

// ---------------- helpers ----------------

__device__ __forceinline__ unsigned short f2bf(float f) {
    union { float f; unsigned u; } v; v.f = f;
    unsigned r = v.u + 0x7FFF + ((v.u >> 16) & 1);   // round-to-nearest-even
    return (unsigned short)(r >> 16);
}
__device__ __forceinline__ float bf2f(unsigned short h) {
    union { unsigned u; float f; } v; v.u = ((unsigned)h) << 16;
    return v.f;
}

typedef const __attribute__((address_space(1))) unsigned int* gas_ptr;
typedef __attribute__((address_space(3))) unsigned int* las_ptr;
__device__ __forceinline__ void lds_load16(const void* g, void* l) {
    __builtin_amdgcn_global_load_lds((gas_ptr)g, (las_ptr)l, 16, 0, 0);
}

__device__ __forceinline__ void split_f8(float4 a, float4 b, short8& hi, short8& lo) {
    float f[8] = {a.x, a.y, a.z, a.w, b.x, b.y, b.z, b.w};
#pragma unroll
    for (int i = 0; i < 8; ++i) {
        unsigned short h = f2bf(f[i]);
        hi[i] = (short)h;
        lo[i] = (short)f2bf(f[i] - bf2f(h));
    }
}

// ---------------- preprocessing: degree, CSR build ----------------

__global__ void zero_kernel(int* counts, int* fillpos, int n) {
    int i = blockIdx.x * 256 + threadIdx.x;
    if (i < n) { counts[i] = 0; fillpos[i] = 0; }
}

__global__ void hist_kernel(const int* __restrict__ dst, int* __restrict__ counts, int E) {
    int e = blockIdx.x * 256 + threadIdx.x;
    if (e < E) atomicAdd(&counts[dst[e]], 1);
}

__global__ void scan_block_kernel(const int* __restrict__ counts, int* __restrict__ row_ptr,
                                  int* __restrict__ blocksums, int n) {
    __shared__ int s[256];
    int tid = threadIdx.x;
    int i = blockIdx.x * 256 + tid;
    int v = (i < n) ? counts[i] : 0;
    s[tid] = v; __syncthreads();
    for (int off = 1; off < 256; off <<= 1) {
        int t = (tid >= off) ? s[tid - off] : 0;
        __syncthreads();
        s[tid] += t;
        __syncthreads();
    }
    if (i < n) row_ptr[i] = s[tid] - v;
    if (tid == 255) blocksums[blockIdx.x] = s[255];
}

__global__ void scan_sums_kernel(const int* __restrict__ blocksums, int* __restrict__ blockoffs, int nb) {
    __shared__ int s[256];
    int tid = threadIdx.x;
    int v = (tid < nb) ? blocksums[tid] : 0;
    s[tid] = v; __syncthreads();
    for (int off = 1; off < 256; off <<= 1) {
        int t = (tid >= off) ? s[tid - off] : 0;
        __syncthreads();
        s[tid] += t;
        __syncthreads();
    }
    blockoffs[tid] = s[tid] - v;
}

__global__ void finalize_rowptr_kernel(int* __restrict__ row_ptr, const int* __restrict__ blockoffs,
                                       const int* __restrict__ counts, float* __restrict__ inv_sqrt,
                                       int n, int E) {
    int i = blockIdx.x * 256 + threadIdx.x;
    if (i < n) {
        row_ptr[i] += blockoffs[i >> 8];
        inv_sqrt[i] = rsqrtf((float)(counts[i] + 1));
    }
    if (i == 0) row_ptr[n] = E;
}

__global__ void fill_kernel(const int* __restrict__ src, const int* __restrict__ dst,
                            const int* __restrict__ row_ptr, int* __restrict__ fillpos,
                            int* __restrict__ src_sorted, int E) {
    int e = blockIdx.x * 256 + threadIdx.x;
    if (e < E) {
        int d = dst[e];
        int pos = row_ptr[d] + atomicAdd(&fillpos[d], 1);
        src_sorted[pos] = src[e];
    }
}

// ---------------- weight split+transpose: W[K][Ncol] fp32 -> Wt_hi/lo [Ncol][K] bf16 ----------------

__global__ void cvt_w_kernel(const float* __restrict__ W, unsigned short* __restrict__ hi,
                             unsigned short* __restrict__ lo, int K, int Ncol) {
    int idx = blockIdx.x * 256 + threadIdx.x;
    if (idx >= K * Ncol) return;
    int k = idx / Ncol, n = idx % Ncol;
    float f = W[idx];
    unsigned short h = f2bf(f);
    hi[(size_t)n * K + k] = h;
    lo[(size_t)n * K + k] = f2bf(f - bf2f(h));
}

// ---------------- split-bf16 MFMA GEMM ----------------
// C[row][col] = (A @ W)[row][col] * inv_sqrt[row], A = Ahi+Alo, W = Whi+Wlo (3 MFMAs)
// 128x128 tile, BK=32, 4 waves, each wave 64x64 = 4x4 frags of 16x16x32.
// LDS fragment-linear per 16-row block: elem(m^,k_local) at 8*m^ + 128*(k_local>>3) + (k_local&7)
//   => a frag read is lane*16B contiguous (ds_read_b128, conflict-free).
// Wt is [n][k] so B-fragments are contiguous 16B runs too.

template<bool A_SPLIT>
__global__ __launch_bounds__(256) void gemm_mfma_kernel(
        const float* __restrict__ Afp,
        const unsigned short* __restrict__ gAhi, const unsigned short* __restrict__ gAlo,
        const unsigned short* __restrict__ Wthi, const unsigned short* __restrict__ Wtlo,
        const float* __restrict__ inv_sqrt, float* __restrict__ C,
        int M, int K, int Ncol) {
    __shared__ unsigned short AhiL[4096], AloL[4096], BhiL[4096], BloL[4096];
    const int tid  = threadIdx.x;
    const int lane = tid & 63;
    const int w    = tid >> 6;        // wave 0..3
    const int wr   = w >> 1, wc = w & 1;
    const int lm   = lane & 15;
    const int lk8  = (lane >> 4) * 8;
    const int bm   = blockIdx.x * 128;
    const int bn   = blockIdx.y * 128;

    f32x4v acc[4][4] = {};

    // --- B staging pointers (wave fills n-blocks 2w, 2w+1, hi+lo) ---
    int nc0 = bn + 16 * (2 * w) + lm;
    int nc1 = bn + 16 * (2 * w + 1) + lm;
    const unsigned short* gB_h0 = Wthi + (size_t)nc0 * K + lk8;
    const unsigned short* gB_h1 = Wthi + (size_t)nc1 * K + lk8;
    const unsigned short* gB_l0 = Wtlo + (size_t)nc0 * K + lk8;
    const unsigned short* gB_l1 = Wtlo + (size_t)nc1 * K + lk8;

    // --- A staging pointers ---
    // A_SPLIT: wave fills m-blocks 2w, 2w+1 via global_load_lds (lane i -> ushort i*8)
    int ar0 = bm + 16 * (2 * w) + lm;     if (ar0 >= M) ar0 = M - 1;
    int ar1 = bm + 16 * (2 * w + 1) + lm; if (ar1 >= M) ar1 = M - 1;
    const unsigned short* gA_h0 = gAhi ? gAhi + (size_t)ar0 * K + lk8 : nullptr;
    const unsigned short* gA_h1 = gAhi ? gAhi + (size_t)ar1 * K + lk8 : nullptr;
    const unsigned short* gA_l0 = gAlo ? gAlo + (size_t)ar0 * K + lk8 : nullptr;
    const unsigned short* gA_l1 = gAlo ? gAlo + (size_t)ar1 * K + lk8 : nullptr;

    // !A_SPLIT: thread converts 16 fp32 of its row: block cb, lane-in-block cs.
    // k segments {cs>>4, (cs>>4)+2}. LDS offsets: 8*cs (= 128*(cs>>4)+8*(cs&15)) and +256.
    const int cb = tid >> 5;
    const int cs = tid & 31;
    int crow = bm + 16 * cb + (cs & 15); if (crow >= M) crow = M - 1;
    const int ck = (cs >> 4) * 8;
    const float* Abase = Afp ? Afp + (size_t)crow * K + ck : nullptr;
    unsigned short* ldsA_hi = &AhiL[cb * 512 + 8 * cs];
    unsigned short* ldsA_lo = &AloL[cb * 512 + 8 * cs];

    for (int k0 = 0; k0 < K; k0 += 32) {
        // ---- stage A ----
        if (A_SPLIT) {
            lds_load16(gA_h0 + k0, &AhiL[(2 * w) * 512]);
            lds_load16(gA_h1 + k0, &AhiL[(2 * w + 1) * 512]);
            lds_load16(gA_l0 + k0, &AloL[(2 * w) * 512]);
            lds_load16(gA_l1 + k0, &AloL[(2 * w + 1) * 512]);
        } else {
            float4 a0 = *(const float4*)(Abase + k0);
            float4 a1 = *(const float4*)(Abase + k0 + 4);
            float4 c0 = *(const float4*)(Abase + k0 + 16);
            float4 c1 = *(const float4*)(Abase + k0 + 20);
            short8 h0, l0, h1, l1;
            split_f8(a0, a1, h0, l0);
            split_f8(c0, c1, h1, l1);
            *(short8*)ldsA_hi         = h0;
            *(short8*)(ldsA_hi + 256) = h1;
            *(short8*)ldsA_lo         = l0;
            *(short8*)(ldsA_lo + 256) = l1;
        }
        // ---- stage B ----
        lds_load16(gB_h0 + k0, &BhiL[(2 * w) * 512]);
        lds_load16(gB_h1 + k0, &BhiL[(2 * w + 1) * 512]);
        lds_load16(gB_l0 + k0, &BloL[(2 * w) * 512]);
        lds_load16(gB_l1 + k0, &BloL[(2 * w + 1) * 512]);
        __syncthreads();

        // ---- fragments ----
        short8 ah[4], av[4], bh[4], bv[4];
#pragma unroll
        for (int i = 0; i < 4; ++i) {
            int ao = (wr * 4 + i) * 512 + lane * 8;
            int bo = (wc * 4 + i) * 512 + lane * 8;
            ah[i] = *(const short8*)&AhiL[ao];
            av[i] = *(const short8*)&AloL[ao];
            bh[i] = *(const short8*)&BhiL[bo];
            bv[i] = *(const short8*)&BloL[bo];
        }
#pragma unroll
        for (int i = 0; i < 4; ++i)
#pragma unroll
            for (int j = 0; j < 4; ++j) {
                acc[i][j] = __builtin_amdgcn_mfma_f32_16x16x32_bf16(ah[i], bh[j], acc[i][j], 0, 0, 0);
                acc[i][j] = __builtin_amdgcn_mfma_f32_16x16x32_bf16(av[i], bh[j], acc[i][j], 0, 0, 0);
                acc[i][j] = __builtin_amdgcn_mfma_f32_16x16x32_bf16(ah[i], bv[j], acc[i][j], 0, 0, 0);
            }
        __syncthreads();
    }

    // ---- epilogue: C/D layout col=lane&15, row=(lane>>4)*4+r ----
    const int orow_base = bm + wr * 64;
    const int ocol_base = bn + wc * 64 + lm;
    const int rq = (lane >> 4) * 4;
#pragma unroll
    for (int i = 0; i < 4; ++i) {
#pragma unroll
        for (int r = 0; r < 4; ++r) {
            int row = orow_base + i * 16 + rq + r;
            if (row >= M) continue;
            float s = inv_sqrt[row];
            size_t rb = (size_t)row * Ncol;
#pragma unroll
            for (int j = 0; j < 4; ++j)
                C[rb + ocol_base + j * 16] = acc[i][j][r] * s;
        }
    }
}

// ---------------- fp32 vector GEMM for layer 3 (A given as hi/lo bf16) ----------------

__global__ __launch_bounds__(256) void gemm_scaled_hl_kernel(
        const unsigned short* __restrict__ Ahi, const unsigned short* __restrict__ Alo,
        const float* __restrict__ W,
        const float* __restrict__ inv_sqrt, float* __restrict__ C,
        int M, int K, int Ncol) {
    __shared__ float As[16][64];
    __shared__ float Ws[16][64];
    int tid = threadIdx.x;
    int tm = tid >> 4;
    int tn = tid & 15;
    int bm = blockIdx.x * 64;
    int bn = blockIdx.y * 64;

    float acc[4][4] = {};

    int lr = tid >> 2;
    int lc = (tid & 3) << 2;
    int wr = tid >> 4;
    int wc = (tid & 15) << 2;
    int arow = bm + lr;
    bool aok = arow < M;
    bool wok = (bn + wc) < Ncol;
    const unsigned short* AhiRow = Ahi + (size_t)arow * K + lc;
    const unsigned short* AloRow = Alo + (size_t)arow * K + lc;

    for (int k0 = 0; k0 < K; k0 += 16) {
        float4 av = make_float4(0.f, 0.f, 0.f, 0.f);
        if (aok) {
            ushort4 hv = *(const ushort4*)(AhiRow + k0);
            ushort4 lv = *(const ushort4*)(AloRow + k0);
            av.x = bf2f(hv.x) + bf2f(lv.x);
            av.y = bf2f(hv.y) + bf2f(lv.y);
            av.z = bf2f(hv.z) + bf2f(lv.z);
            av.w = bf2f(hv.w) + bf2f(lv.w);
        }
        As[lc + 0][lr] = av.x; As[lc + 1][lr] = av.y;
        As[lc + 2][lr] = av.z; As[lc + 3][lr] = av.w;

        float4 wv = make_float4(0.f, 0.f, 0.f, 0.f);
        if (wok) wv = *(const float4*)(W + (size_t)(k0 + wr) * Ncol + bn + wc);
        *(float4*)&Ws[wr][wc] = wv;
        __syncthreads();

#pragma unroll
        for (int k = 0; k < 16; ++k) {
            const float4 a4 = *(const float4*)&As[k][tm << 2];
            const float4 b4 = *(const float4*)&Ws[k][tn << 2];
            float a[4] = {a4.x, a4.y, a4.z, a4.w};
            float b[4] = {b4.x, b4.y, b4.z, b4.w};
#pragma unroll
            for (int i = 0; i < 4; ++i)
#pragma unroll
                for (int j = 0; j < 4; ++j)
                    acc[i][j] = fmaf(a[i], b[j], acc[i][j]);
        }
        __syncthreads();
    }

#pragma unroll
    for (int i = 0; i < 4; ++i) {
        int row = bm + (tm << 2) + i;
        if (row >= M) continue;
        float s = inv_sqrt[row];
        int col = bn + (tn << 2);
        if (col < Ncol) {
            float4 o = make_float4(acc[i][0] * s, acc[i][1] * s, acc[i][2] * s, acc[i][3] * s);
            *(float4*)&C[(size_t)row * Ncol + col] = o;
        }
    }
}

// ---------------- aggregation (H=256): one wave per node; writes hi/lo bf16 ----------------

__global__ __launch_bounds__(256) void agg_bn_hl_kernel(
        const float* __restrict__ g, const int* __restrict__ row_ptr,
        const int* __restrict__ srcs, const float* __restrict__ inv_sqrt,
        const float* __restrict__ bias, const float* __restrict__ gamma,
        const float* __restrict__ beta, const float* __restrict__ mean,
        const float* __restrict__ var,
        unsigned short* __restrict__ out_hi, unsigned short* __restrict__ out_lo, int n) {
    int node = (blockIdx.x << 2) + (threadIdx.x >> 6);
    int lane = threadIdx.x & 63;
    if (node >= n) return;
    const float4* gp = (const float4*)g;
    float4 acc = gp[(size_t)node * 64 + lane];
    int beg = row_ptr[node], end = row_ptr[node + 1];
    for (int e = beg; e < end; ++e) {
        int s = srcs[e];
        float4 v = gp[(size_t)s * 64 + lane];
        acc.x += v.x; acc.y += v.y; acc.z += v.z; acc.w += v.w;
    }
    float inv = inv_sqrt[node];
    float4 b4  = ((const float4*)bias)[lane];
    float4 ga4 = ((const float4*)gamma)[lane];
    float4 be4 = ((const float4*)beta)[lane];
    float4 m4  = ((const float4*)mean)[lane];
    float4 v4  = ((const float4*)var)[lane];
    float4 o;
    o.x = fmaxf((acc.x * inv + b4.x - m4.x) * (ga4.x * rsqrtf(v4.x + EPS)) + be4.x, 0.f);
    o.y = fmaxf((acc.y * inv + b4.y - m4.y) * (ga4.y * rsqrtf(v4.y + EPS)) + be4.y, 0.f);
    o.z = fmaxf((acc.z * inv + b4.z - m4.z) * (ga4.z * rsqrtf(v4.z + EPS)) + be4.z, 0.f);
    o.w = fmaxf((acc.w * inv + b4.w - m4.w) * (ga4.w * rsqrtf(v4.w + EPS)) + be4.w, 0.f);
    ushort4 oh, ol;
    oh.x = f2bf(o.x); ol.x = f2bf(o.x - bf2f(oh.x));
    oh.y = f2bf(o.y); ol.y = f2bf(o.y - bf2f(oh.y));
    oh.z = f2bf(o.z); ol.z = f2bf(o.z - bf2f(oh.z));
    oh.w = f2bf(o.w); ol.w = f2bf(o.w - bf2f(oh.w));
    ((ushort4*)out_hi)[(size_t)node * 64 + lane] = oh;
    ((ushort4*)out_lo)[(size_t)node * 64 + lane] = ol;
}

// ---------------- final aggregation (C=40) ----------------

__global__ __launch_bounds__(256) void agg_final_kernel(
        const float* __restrict__ g, const int* __restrict__ row_ptr,
        const int* __restrict__ srcs, const float* __restrict__ inv_sqrt,
        const float* __restrict__ bias, float* __restrict__ out, int n) {
    int node = (blockIdx.x << 2) + (threadIdx.x >> 6);
    int lane = threadIdx.x & 63;
    if (node >= n || lane >= CLS) return;
    float acc = g[(size_t)node * CLS + lane];
    int beg = row_ptr[node], end = row_ptr[node + 1];
    for (int e = beg; e < end; ++e)
        acc += g[(size_t)srcs[e] * CLS + lane];
    out[(size_t)node * CLS + lane] = acc * inv_sqrt[node] + bias[lane];
}

// ---------------- launch ----------------

extern "C" void kernel_launch(void* const* d_in, const int* in_sizes, int n_in,
                              void* d_out, int out_size, void* d_ws, size_t ws_size,
                              hipStream_t stream) {
    const float* x     = (const float*)d_in[0];
    const int*   edges = (const int*)d_in[1];
    const float* W1    = (const float*)d_in[2];
    const float* b1    = (const float*)d_in[3];
    const float* W2    = (const float*)d_in[4];
    const float* b2    = (const float*)d_in[5];
    const float* W3    = (const float*)d_in[6];
    const float* b3    = (const float*)d_in[7];
    const float* gamma = (const float*)d_in[8];
    const float* beta  = (const float*)d_in[9];
    const float* mean  = (const float*)d_in[10];
    const float* var   = (const float*)d_in[11];

    const int N = in_sizes[0] / FEAT;   // 50000
    const int E = in_sizes[1] / 2;      // 800000
    const int* src = edges;
    const int* dst = edges + E;

    char* ws = (char*)d_ws;
    auto alloc = [&](size_t bytes) -> char* {
        char* p = ws;
        ws += (bytes + 255) & ~(size_t)255;
        return p;
    };
    int*   counts     = (int*)  alloc((size_t)N * 4);
    int*   fillpos    = (int*)  alloc((size_t)N * 4);
    int*   row_ptr    = (int*)  alloc((size_t)(N + 1) * 4);
    int*   blocksums  = (int*)  alloc(256 * 4);
    int*   blockoffs  = (int*)  alloc(256 * 4);
    float* inv_sqrt   = (float*)alloc((size_t)N * 4);
    int*   src_sorted = (int*)  alloc((size_t)E * 4);
    unsigned short* w1hi = (unsigned short*)alloc((size_t)FEAT * HID * 2);
    unsigned short* w1lo = (unsigned short*)alloc((size_t)FEAT * HID * 2);
    unsigned short* w2hi = (unsigned short*)alloc((size_t)HID * HID * 2);
    unsigned short* w2lo = (unsigned short*)alloc((size_t)HID * HID * 2);
    float*          g    = (float*)alloc((size_t)N * HID * 4);          // 51.2 MB
    unsigned short* h_hi = (unsigned short*)alloc((size_t)N * HID * 2); // 25.6 MB
    unsigned short* h_lo = (unsigned short*)alloc((size_t)N * HID * 2); // 25.6 MB

    int nb = (N + 255) / 256;
    int eb = (E + 255) / 256;

    zero_kernel<<<nb, 256, 0, stream>>>(counts, fillpos, N);
    hist_kernel<<<eb, 256, 0, stream>>>(dst, counts, E);
    scan_block_kernel<<<nb, 256, 0, stream>>>(counts, row_ptr, blocksums, N);
    scan_sums_kernel<<<1, 256, 0, stream>>>(blocksums, blockoffs, nb);
    finalize_rowptr_kernel<<<nb, 256, 0, stream>>>(row_ptr, blockoffs, counts, inv_sqrt, N, E);
    fill_kernel<<<eb, 256, 0, stream>>>(src, dst, row_ptr, fillpos, src_sorted, E);

    cvt_w_kernel<<<(FEAT * HID + 255) / 256, 256, 0, stream>>>(W1, w1hi, w1lo, FEAT, HID);
    cvt_w_kernel<<<(HID * HID + 255) / 256, 256, 0, stream>>>(W2, w2hi, w2lo, HID, HID);

    dim3 mfma_grid((N + 127) / 128, HID / 128);
    dim3 gemm3_grid((N + 63) / 64, 1);
    dim3 agg_grid((N + 3) / 4);

    // layer 1: A = x fp32 (on-the-fly split)
    gemm_mfma_kernel<false><<<mfma_grid, 256, 0, stream>>>(
        x, nullptr, nullptr, w1hi, w1lo, inv_sqrt, g, N, FEAT, HID);
    agg_bn_hl_kernel<<<agg_grid, 256, 0, stream>>>(g, row_ptr, src_sorted, inv_sqrt,
                                                   b1, gamma, beta, mean, var, h_hi, h_lo, N);
    // layer 2: A = h1 (pre-split)
    gemm_mfma_kernel<true><<<mfma_grid, 256, 0, stream>>>(
        nullptr, h_hi, h_lo, w2hi, w2lo, inv_sqrt, g, N, HID, HID);
    agg_bn_hl_kernel<<<agg_grid, 256, 0, stream>>>(g, row_ptr, src_sorted, inv_sqrt,
                                                   b2, gamma, beta, mean, var, h_hi, h_lo, N);
    // layer 3: fp32 vector GEMM reading hi/lo, then final aggregation
    gemm_scaled_hl_kernel<<<gemm3_grid, 256, 0, stream>>>(h_hi, h_lo, W3, inv_sqrt, g, N, HID, CLS);
    agg_final_kernel<<<agg_grid, 256, 0, stream>>>(g, row_ptr, src_sorted, inv_sqrt,
                                                   b3, (float*)d_out, N);
}

// Round 4
// 668.173 us; speedup vs baseline: 1.2941x; 1.0675x over previous
//
#include <hip/hip_runtime.h>
#include <cstdint>
#include <cstddef>

#define FEAT 512
#define HID 256
#define CLS 40
#define EPS 1e-5f

typedef __attribute__((ext_vector_type(8))) short short8;
typedef __attribute__((ext_vector_type(4))) float f32x4v;

// ---------------- helpers ----------------

__device__ __forceinline__ unsigned short f2bf(float f) {
    union { float f; unsigned u; } v; v.f = f;
    unsigned r = v.u + 0x7FFF + ((v.u >> 16) & 1);   // round-to-nearest-even
    return (unsigned short)(r >> 16);
}
__device__ __forceinline__ float bf2f(unsigned short h) {
    union { unsigned u; float f; } v; v.u = ((unsigned)h) << 16;
    return v.f;
}

typedef const __attribute__((address_space(1))) unsigned int* gas_ptr;
typedef __attribute__((address_space(3))) unsigned int* las_ptr;
__device__ __forceinline__ void lds_load16(const void* g, void* l) {
    __builtin_amdgcn_global_load_lds((gas_ptr)g, (las_ptr)l, 16, 0, 0);
}

__device__ __forceinline__ void split_f8(float4 a, float4 b, short8& hi, short8& lo) {
    float f[8] = {a.x, a.y, a.z, a.w, b.x, b.y, b.z, b.w};
#pragma unroll
    for (int i = 0; i < 8; ++i) {
        unsigned short h = f2bf(f[i]);
        hi[i] = (short)h;
        lo[i] = (short)f2bf(f[i] - bf2f(h));
    }
}

__device__ __forceinline__ float4 f4add(float4 a, float4 b) {
    return make_float4(a.x + b.x, a.y + b.y, a.z + b.z, a.w + b.w);
}

// ---------------- preprocessing: degree, CSR build ----------------

__global__ void zero_kernel(int* counts, int* fillpos, int n) {
    int i = blockIdx.x * 256 + threadIdx.x;
    if (i < n) { counts[i] = 0; fillpos[i] = 0; }
}

__global__ void hist_kernel(const int* __restrict__ dst, int* __restrict__ counts, int E) {
    int e = blockIdx.x * 256 + threadIdx.x;
    if (e < E) atomicAdd(&counts[dst[e]], 1);
}

__global__ void scan_block_kernel(const int* __restrict__ counts, int* __restrict__ row_ptr,
                                  int* __restrict__ blocksums, int n) {
    __shared__ int s[256];
    int tid = threadIdx.x;
    int i = blockIdx.x * 256 + tid;
    int v = (i < n) ? counts[i] : 0;
    s[tid] = v; __syncthreads();
    for (int off = 1; off < 256; off <<= 1) {
        int t = (tid >= off) ? s[tid - off] : 0;
        __syncthreads();
        s[tid] += t;
        __syncthreads();
    }
    if (i < n) row_ptr[i] = s[tid] - v;
    if (tid == 255) blocksums[blockIdx.x] = s[255];
}

__global__ void scan_sums_kernel(const int* __restrict__ blocksums, int* __restrict__ blockoffs, int nb) {
    __shared__ int s[256];
    int tid = threadIdx.x;
    int v = (tid < nb) ? blocksums[tid] : 0;
    s[tid] = v; __syncthreads();
    for (int off = 1; off < 256; off <<= 1) {
        int t = (tid >= off) ? s[tid - off] : 0;
        __syncthreads();
        s[tid] += t;
        __syncthreads();
    }
    blockoffs[tid] = s[tid] - v;
}

__global__ void finalize_rowptr_kernel(int* __restrict__ row_ptr, const int* __restrict__ blockoffs,
                                       const int* __restrict__ counts, float* __restrict__ inv_sqrt,
                                       int n, int E) {
    int i = blockIdx.x * 256 + threadIdx.x;
    if (i < n) {
        row_ptr[i] += blockoffs[i >> 8];
        inv_sqrt[i] = rsqrtf((float)(counts[i] + 1));
    }
    if (i == 0) row_ptr[n] = E;
}

__global__ void fill_kernel(const int* __restrict__ src, const int* __restrict__ dst,
                            const int* __restrict__ row_ptr, int* __restrict__ fillpos,
                            int* __restrict__ src_sorted, int E) {
    int e = blockIdx.x * 256 + threadIdx.x;
    if (e < E) {
        int d = dst[e];
        int pos = row_ptr[d] + atomicAdd(&fillpos[d], 1);
        src_sorted[pos] = src[e];
    }
}

// ---------------- weight split+transpose: W[K][Ncol] fp32 -> Wt_hi/lo [Ncol][K] bf16 ----------------

__global__ void cvt_w_kernel(const float* __restrict__ W, unsigned short* __restrict__ hi,
                             unsigned short* __restrict__ lo, int K, int Ncol) {
    int idx = blockIdx.x * 256 + threadIdx.x;
    if (idx >= K * Ncol) return;
    int k = idx / Ncol, n = idx % Ncol;
    float f = W[idx];
    unsigned short h = f2bf(f);
    hi[(size_t)n * K + k] = h;
    lo[(size_t)n * K + k] = f2bf(f - bf2f(h));
}

// ---------------- split-bf16 MFMA GEMM ----------------
// C[row][col] = (A @ W)[row][col] * inv_sqrt[row], A = Ahi+Alo, W = Whi+Wlo (3 MFMAs)
// 128x128 tile, BK=32, 4 waves, each wave 64x64 = 4x4 frags of 16x16x32.
// LDS fragment-linear per 16-row block: elem(m^,k_local) at 8*m^ + 128*(k_local>>3) + (k_local&7)
//   => a frag read is lane*16B contiguous (ds_read_b128, conflict-free).
// Wt is [n][k] so B-fragments are contiguous 16B runs too.

template<bool A_SPLIT>
__global__ __launch_bounds__(256) void gemm_mfma_kernel(
        const float* __restrict__ Afp,
        const unsigned short* __restrict__ gAhi, const unsigned short* __restrict__ gAlo,
        const unsigned short* __restrict__ Wthi, const unsigned short* __restrict__ Wtlo,
        const float* __restrict__ inv_sqrt, float* __restrict__ C,
        int M, int K, int Ncol) {
    __shared__ unsigned short AhiL[4096], AloL[4096], BhiL[4096], BloL[4096];
    const int tid  = threadIdx.x;
    const int lane = tid & 63;
    const int w    = tid >> 6;        // wave 0..3
    const int wr   = w >> 1, wc = w & 1;
    const int lm   = lane & 15;
    const int lk8  = (lane >> 4) * 8;
    const int bm   = blockIdx.x * 128;
    const int bn   = blockIdx.y * 128;

    f32x4v acc[4][4] = {};

    // --- B staging pointers (wave fills n-blocks 2w, 2w+1, hi+lo) ---
    int nc0 = bn + 16 * (2 * w) + lm;
    int nc1 = bn + 16 * (2 * w + 1) + lm;
    const unsigned short* gB_h0 = Wthi + (size_t)nc0 * K + lk8;
    const unsigned short* gB_h1 = Wthi + (size_t)nc1 * K + lk8;
    const unsigned short* gB_l0 = Wtlo + (size_t)nc0 * K + lk8;
    const unsigned short* gB_l1 = Wtlo + (size_t)nc1 * K + lk8;

    // --- A staging pointers ---
    // A_SPLIT: wave fills m-blocks 2w, 2w+1 via global_load_lds (lane i -> ushort i*8)
    int ar0 = bm + 16 * (2 * w) + lm;     if (ar0 >= M) ar0 = M - 1;
    int ar1 = bm + 16 * (2 * w + 1) + lm; if (ar1 >= M) ar1 = M - 1;
    const unsigned short* gA_h0 = gAhi ? gAhi + (size_t)ar0 * K + lk8 : nullptr;
    const unsigned short* gA_h1 = gAhi ? gAhi + (size_t)ar1 * K + lk8 : nullptr;
    const unsigned short* gA_l0 = gAlo ? gAlo + (size_t)ar0 * K + lk8 : nullptr;
    const unsigned short* gA_l1 = gAlo ? gAlo + (size_t)ar1 * K + lk8 : nullptr;

    // !A_SPLIT: thread converts 16 fp32 of its row: block cb, lane-in-block cs.
    // k segments {cs>>4, (cs>>4)+2}. LDS offsets: 8*cs (= 128*(cs>>4)+8*(cs&15)) and +256.
    const int cb = tid >> 5;
    const int cs = tid & 31;
    int crow = bm + 16 * cb + (cs & 15); if (crow >= M) crow = M - 1;
    const int ck = (cs >> 4) * 8;
    const float* Abase = Afp ? Afp + (size_t)crow * K + ck : nullptr;
    unsigned short* ldsA_hi = &AhiL[cb * 512 + 8 * cs];
    unsigned short* ldsA_lo = &AloL[cb * 512 + 8 * cs];

    for (int k0 = 0; k0 < K; k0 += 32) {
        // ---- stage A ----
        if (A_SPLIT) {
            lds_load16(gA_h0 + k0, &AhiL[(2 * w) * 512]);
            lds_load16(gA_h1 + k0, &AhiL[(2 * w + 1) * 512]);
            lds_load16(gA_l0 + k0, &AloL[(2 * w) * 512]);
            lds_load16(gA_l1 + k0, &AloL[(2 * w + 1) * 512]);
        } else {
            float4 a0 = *(const float4*)(Abase + k0);
            float4 a1 = *(const float4*)(Abase + k0 + 4);
            float4 c0 = *(const float4*)(Abase + k0 + 16);
            float4 c1 = *(const float4*)(Abase + k0 + 20);
            short8 h0, l0, h1, l1;
            split_f8(a0, a1, h0, l0);
            split_f8(c0, c1, h1, l1);
            *(short8*)ldsA_hi         = h0;
            *(short8*)(ldsA_hi + 256) = h1;
            *(short8*)ldsA_lo         = l0;
            *(short8*)(ldsA_lo + 256) = l1;
        }
        // ---- stage B ----
        lds_load16(gB_h0 + k0, &BhiL[(2 * w) * 512]);
        lds_load16(gB_h1 + k0, &BhiL[(2 * w + 1) * 512]);
        lds_load16(gB_l0 + k0, &BloL[(2 * w) * 512]);
        lds_load16(gB_l1 + k0, &BloL[(2 * w + 1) * 512]);
        __syncthreads();

        // ---- fragments ----
        short8 ah[4], av[4], bh[4], bv[4];
#pragma unroll
        for (int i = 0; i < 4; ++i) {
            int ao = (wr * 4 + i) * 512 + lane * 8;
            int bo = (wc * 4 + i) * 512 + lane * 8;
            ah[i] = *(const short8*)&AhiL[ao];
            av[i] = *(const short8*)&AloL[ao];
            bh[i] = *(const short8*)&BhiL[bo];
            bv[i] = *(const short8*)&BloL[bo];
        }
#pragma unroll
        for (int i = 0; i < 4; ++i)
#pragma unroll
            for (int j = 0; j < 4; ++j) {
                acc[i][j] = __builtin_amdgcn_mfma_f32_16x16x32_bf16(ah[i], bh[j], acc[i][j], 0, 0, 0);
                acc[i][j] = __builtin_amdgcn_mfma_f32_16x16x32_bf16(av[i], bh[j], acc[i][j], 0, 0, 0);
                acc[i][j] = __builtin_amdgcn_mfma_f32_16x16x32_bf16(ah[i], bv[j], acc[i][j], 0, 0, 0);
            }
        __syncthreads();
    }

    // ---- epilogue: C/D layout col=lane&15, row=(lane>>4)*4+r ----
    const int orow_base = bm + wr * 64;
    const int ocol_base = bn + wc * 64 + lm;
    const int rq = (lane >> 4) * 4;
#pragma unroll
    for (int i = 0; i < 4; ++i) {
#pragma unroll
        for (int r = 0; r < 4; ++r) {
            int row = orow_base + i * 16 + rq + r;
            if (row >= M) continue;
            float s = inv_sqrt[row];
            size_t rb = (size_t)row * Ncol;
#pragma unroll
            for (int j = 0; j < 4; ++j)
                C[rb + ocol_base + j * 16] = acc[i][j][r] * s;
        }
    }
}

// ---------------- fp32 vector GEMM for layer 3 (A given as hi/lo bf16) ----------------

__global__ __launch_bounds__(256) void gemm_scaled_hl_kernel(
        const unsigned short* __restrict__ Ahi, const unsigned short* __restrict__ Alo,
        const float* __restrict__ W,
        const float* __restrict__ inv_sqrt, float* __restrict__ C,
        int M, int K, int Ncol) {
    __shared__ float As[16][64];
    __shared__ float Ws[16][64];
    int tid = threadIdx.x;
    int tm = tid >> 4;
    int tn = tid & 15;
    int bm = blockIdx.x * 64;
    int bn = blockIdx.y * 64;

    float acc[4][4] = {};

    int lr = tid >> 2;
    int lc = (tid & 3) << 2;
    int wr = tid >> 4;
    int wc = (tid & 15) << 2;
    int arow = bm + lr;
    bool aok = arow < M;
    bool wok = (bn + wc) < Ncol;
    const unsigned short* AhiRow = Ahi + (size_t)arow * K + lc;
    const unsigned short* AloRow = Alo + (size_t)arow * K + lc;

    for (int k0 = 0; k0 < K; k0 += 16) {
        float4 av = make_float4(0.f, 0.f, 0.f, 0.f);
        if (aok) {
            ushort4 hv = *(const ushort4*)(AhiRow + k0);
            ushort4 lv = *(const ushort4*)(AloRow + k0);
            av.x = bf2f(hv.x) + bf2f(lv.x);
            av.y = bf2f(hv.y) + bf2f(lv.y);
            av.z = bf2f(hv.z) + bf2f(lv.z);
            av.w = bf2f(hv.w) + bf2f(lv.w);
        }
        As[lc + 0][lr] = av.x; As[lc + 1][lr] = av.y;
        As[lc + 2][lr] = av.z; As[lc + 3][lr] = av.w;

        float4 wv = make_float4(0.f, 0.f, 0.f, 0.f);
        if (wok) wv = *(const float4*)(W + (size_t)(k0 + wr) * Ncol + bn + wc);
        *(float4*)&Ws[wr][wc] = wv;
        __syncthreads();

#pragma unroll
        for (int k = 0; k < 16; ++k) {
            const float4 a4 = *(const float4*)&As[k][tm << 2];
            const float4 b4 = *(const float4*)&Ws[k][tn << 2];
            float a[4] = {a4.x, a4.y, a4.z, a4.w};
            float b[4] = {b4.x, b4.y, b4.z, b4.w};
#pragma unroll
            for (int i = 0; i < 4; ++i)
#pragma unroll
                for (int j = 0; j < 4; ++j)
                    acc[i][j] = fmaf(a[i], b[j], acc[i][j]);
        }
        __syncthreads();
    }

#pragma unroll
    for (int i = 0; i < 4; ++i) {
        int row = bm + (tm << 2) + i;
        if (row >= M) continue;
        float s = inv_sqrt[row];
        int col = bn + (tn << 2);
        if (col < Ncol) {
            float4 o = make_float4(acc[i][0] * s, acc[i][1] * s, acc[i][2] * s, acc[i][3] * s);
            *(float4*)&C[(size_t)row * Ncol + col] = o;
        }
    }
}

// ---------------- aggregation (H=256): one wave per node; writes hi/lo bf16 ----------------
// Indices batch-loaded 64/wave + __shfl broadcast; gathers unrolled 8-wide for MLP.

__global__ __launch_bounds__(256) void agg_bn_hl_kernel(
        const float* __restrict__ g, const int* __restrict__ row_ptr,
        const int* __restrict__ srcs, const float* __restrict__ inv_sqrt,
        const float* __restrict__ bias, const float* __restrict__ gamma,
        const float* __restrict__ beta, const float* __restrict__ mean,
        const float* __restrict__ var,
        unsigned short* __restrict__ out_hi, unsigned short* __restrict__ out_lo, int n) {
    int node = (blockIdx.x << 2) + (threadIdx.x >> 6);
    int lane = threadIdx.x & 63;
    if (node >= n) return;
    const float4* gp = (const float4*)g;
    float4 acc0 = gp[(size_t)node * 64 + lane];   // self-loop
    float4 acc1 = make_float4(0.f, 0.f, 0.f, 0.f);
    int beg = row_ptr[node];
    int cnt = row_ptr[node + 1] - beg;

    for (int base = 0; base < cnt; base += 64) {
        int m = cnt - base; if (m > 64) m = 64;
        int idx = (lane < m) ? srcs[beg + base + lane] : 0;
        int j = 0;
        for (; j + 8 <= m; j += 8) {
            int s0 = __shfl(idx, j + 0), s1 = __shfl(idx, j + 1);
            int s2 = __shfl(idx, j + 2), s3 = __shfl(idx, j + 3);
            int s4 = __shfl(idx, j + 4), s5 = __shfl(idx, j + 5);
            int s6 = __shfl(idx, j + 6), s7 = __shfl(idx, j + 7);
            float4 v0 = gp[(size_t)s0 * 64 + lane];
            float4 v1 = gp[(size_t)s1 * 64 + lane];
            float4 v2 = gp[(size_t)s2 * 64 + lane];
            float4 v3 = gp[(size_t)s3 * 64 + lane];
            float4 v4 = gp[(size_t)s4 * 64 + lane];
            float4 v5 = gp[(size_t)s5 * 64 + lane];
            float4 v6 = gp[(size_t)s6 * 64 + lane];
            float4 v7 = gp[(size_t)s7 * 64 + lane];
            acc0 = f4add(acc0, f4add(f4add(v0, v1), f4add(v2, v3)));
            acc1 = f4add(acc1, f4add(f4add(v4, v5), f4add(v6, v7)));
        }
        for (; j < m; ++j) {
            int s = __shfl(idx, j);
            acc0 = f4add(acc0, gp[(size_t)s * 64 + lane]);
        }
    }
    float4 acc = f4add(acc0, acc1);

    float inv = inv_sqrt[node];
    float4 b4  = ((const float4*)bias)[lane];
    float4 ga4 = ((const float4*)gamma)[lane];
    float4 be4 = ((const float4*)beta)[lane];
    float4 m4  = ((const float4*)mean)[lane];
    float4 v4  = ((const float4*)var)[lane];
    float4 o;
    o.x = fmaxf((acc.x * inv + b4.x - m4.x) * (ga4.x * rsqrtf(v4.x + EPS)) + be4.x, 0.f);
    o.y = fmaxf((acc.y * inv + b4.y - m4.y) * (ga4.y * rsqrtf(v4.y + EPS)) + be4.y, 0.f);
    o.z = fmaxf((acc.z * inv + b4.z - m4.z) * (ga4.z * rsqrtf(v4.z + EPS)) + be4.z, 0.f);
    o.w = fmaxf((acc.w * inv + b4.w - m4.w) * (ga4.w * rsqrtf(v4.w + EPS)) + be4.w, 0.f);
    ushort4 oh, ol;
    oh.x = f2bf(o.x); ol.x = f2bf(o.x - bf2f(oh.x));
    oh.y = f2bf(o.y); ol.y = f2bf(o.y - bf2f(oh.y));
    oh.z = f2bf(o.z); ol.z = f2bf(o.z - bf2f(oh.z));
    oh.w = f2bf(o.w); ol.w = f2bf(o.w - bf2f(oh.w));
    ((ushort4*)out_hi)[(size_t)node * 64 + lane] = oh;
    ((ushort4*)out_lo)[(size_t)node * 64 + lane] = ol;
}

// ---------------- final aggregation (C=40): all 64 lanes stay alive for shfl ----------------

__global__ __launch_bounds__(256) void agg_final_kernel(
        const float* __restrict__ g, const int* __restrict__ row_ptr,
        const int* __restrict__ srcs, const float* __restrict__ inv_sqrt,
        const float* __restrict__ bias, float* __restrict__ out, int n) {
    int node = (blockIdx.x << 2) + (threadIdx.x >> 6);
    int lane = threadIdx.x & 63;
    if (node >= n) return;
    int flane = (lane < CLS) ? lane : 0;       // clamped gather lane; store masked below
    float acc0 = g[(size_t)node * CLS + flane];
    float acc1 = 0.f;
    int beg = row_ptr[node];
    int cnt = row_ptr[node + 1] - beg;

    for (int base = 0; base < cnt; base += 64) {
        int m = cnt - base; if (m > 64) m = 64;
        int idx = (lane < m) ? srcs[beg + base + lane] : 0;
        int j = 0;
        for (; j + 8 <= m; j += 8) {
            int s0 = __shfl(idx, j + 0), s1 = __shfl(idx, j + 1);
            int s2 = __shfl(idx, j + 2), s3 = __shfl(idx, j + 3);
            int s4 = __shfl(idx, j + 4), s5 = __shfl(idx, j + 5);
            int s6 = __shfl(idx, j + 6), s7 = __shfl(idx, j + 7);
            float v0 = g[(size_t)s0 * CLS + flane];
            float v1 = g[(size_t)s1 * CLS + flane];
            float v2 = g[(size_t)s2 * CLS + flane];
            float v3 = g[(size_t)s3 * CLS + flane];
            float v4 = g[(size_t)s4 * CLS + flane];
            float v5 = g[(size_t)s5 * CLS + flane];
            float v6 = g[(size_t)s6 * CLS + flane];
            float v7 = g[(size_t)s7 * CLS + flane];
            acc0 += (v0 + v1) + (v2 + v3);
            acc1 += (v4 + v5) + (v6 + v7);
        }
        for (; j < m; ++j) {
            int s = __shfl(idx, j);
            acc0 += g[(size_t)s * CLS + flane];
        }
    }
    if (lane < CLS)
        out[(size_t)node * CLS + lane] = (acc0 + acc1) * inv_sqrt[node] + bias[lane];
}

// ---------------- launch ----------------

extern "C" void kernel_launch(void* const* d_in, const int* in_sizes, int n_in,
                              void* d_out, int out_size, void* d_ws, size_t ws_size,
                              hipStream_t stream) {
    const float* x     = (const float*)d_in[0];
    const int*   edges = (const int*)d_in[1];
    const float* W1    = (const float*)d_in[2];
    const float* b1    = (const float*)d_in[3];
    const float* W2    = (const float*)d_in[4];
    const float* b2    = (const float*)d_in[5];
    const float* W3    = (const float*)d_in[6];
    const float* b3    = (const float*)d_in[7];
    const float* gamma = (const float*)d_in[8];
    const float* beta  = (const float*)d_in[9];
    const float* mean  = (const float*)d_in[10];
    const float* var   = (const float*)d_in[11];

    const int N = in_sizes[0] / FEAT;   // 50000
    const int E = in_sizes[1] / 2;      // 800000
    const int* src = edges;
    const int* dst = edges + E;

    char* ws = (char*)d_ws;
    auto alloc = [&](size_t bytes) -> char* {
        char* p = ws;
        ws += (bytes + 255) & ~(size_t)255;
        return p;
    };
    int*   counts     = (int*)  alloc((size_t)N * 4);
    int*   fillpos    = (int*)  alloc((size_t)N * 4);
    int*   row_ptr    = (int*)  alloc((size_t)(N + 1) * 4);
    int*   blocksums  = (int*)  alloc(256 * 4);
    int*   blockoffs  = (int*)  alloc(256 * 4);
    float* inv_sqrt   = (float*)alloc((size_t)N * 4);
    int*   src_sorted = (int*)  alloc((size_t)E * 4);
    unsigned short* w1hi = (unsigned short*)alloc((size_t)FEAT * HID * 2);
    unsigned short* w1lo = (unsigned short*)alloc((size_t)FEAT * HID * 2);
    unsigned short* w2hi = (unsigned short*)alloc((size_t)HID * HID * 2);
    unsigned short* w2lo = (unsigned short*)alloc((size_t)HID * HID * 2);
    float*          g    = (float*)alloc((size_t)N * HID * 4);          // 51.2 MB
    unsigned short* h_hi = (unsigned short*)alloc((size_t)N * HID * 2); // 25.6 MB
    unsigned short* h_lo = (unsigned short*)alloc((size_t)N * HID * 2); // 25.6 MB

    int nb = (N + 255) / 256;
    int eb = (E + 255) / 256;

    zero_kernel<<<nb, 256, 0, stream>>>(counts, fillpos, N);
    hist_kernel<<<eb, 256, 0, stream>>>(dst, counts, E);
    scan_block_kernel<<<nb, 256, 0, stream>>>(counts, row_ptr, blocksums, N);
    scan_sums_kernel<<<1, 256, 0, stream>>>(blocksums, blockoffs, nb);
    finalize_rowptr_kernel<<<nb, 256, 0, stream>>>(row_ptr, blockoffs, counts, inv_sqrt, N, E);
    fill_kernel<<<eb, 256, 0, stream>>>(src, dst, row_ptr, fillpos, src_sorted, E);

    cvt_w_kernel<<<(FEAT * HID + 255) / 256, 256, 0, stream>>>(W1, w1hi, w1lo, FEAT, HID);
    cvt_w_kernel<<<(HID * HID + 255) / 256, 256, 0, stream>>>(W2, w2hi, w2lo, HID, HID);

    dim3 mfma_grid((N + 127) / 128, HID / 128);
    dim3 gemm3_grid((N + 63) / 64, 1);
    dim3 agg_grid((N + 3) / 4);

    // layer 1: A = x fp32 (on-the-fly split)
    gemm_mfma_kernel<false><<<mfma_grid, 256, 0, stream>>>(
        x, nullptr, nullptr, w1hi, w1lo, inv_sqrt, g, N, FEAT, HID);
    agg_bn_hl_kernel<<<agg_grid, 256, 0, stream>>>(g, row_ptr, src_sorted, inv_sqrt,
                                                   b1, gamma, beta, mean, var, h_hi, h_lo, N);
    // layer 2: A = h1 (pre-split)
    gemm_mfma_kernel<true><<<mfma_grid, 256, 0, stream>>>(
        nullptr, h_hi, h_lo, w2hi, w2lo, inv_sqrt, g, N, HID, HID);
    agg_bn_hl_kernel<<<agg_grid, 256, 0, stream>>>(g, row_ptr, src_sorted, inv_sqrt,
                                                   b2, gamma, beta, mean, var, h_hi, h_lo, N);
    // layer 3: fp32 vector GEMM reading hi/lo, then final aggregation
    gemm_scaled_hl_kernel<<<gemm3_grid, 256, 0, stream>>>(h_hi, h_lo, W3, inv_sqrt, g, N, HID, CLS);
    agg_final_kernel<<<agg_grid, 256, 0, stream>>>(g, row_ptr, src_sorted, inv_sqrt,
                                                   b3, (float*)d_out, N);
}

// Round 5
// 550.038 us; speedup vs baseline: 1.5721x; 1.2148x over previous
//
#include <hip/hip_runtime.h>
#include <cstdint>
#include <cstddef>

#define FEAT 512
#define HID 256
#define CLS 40
#define EPS 1e-5f

typedef __attribute__((ext_vector_type(8))) short short8;
typedef __attribute__((ext_vector_type(4))) float f32x4v;

// ---------------- helpers ----------------

__device__ __forceinline__ unsigned short f2bf(float f) {
    union { float f; unsigned u; } v; v.f = f;
    unsigned r = v.u + 0x7FFF + ((v.u >> 16) & 1);   // round-to-nearest-even
    return (unsigned short)(r >> 16);
}
__device__ __forceinline__ float bf2f(unsigned short h) {
    union { unsigned u; float f; } v; v.u = ((unsigned)h) << 16;
    return v.f;
}

typedef const __attribute__((address_space(1))) unsigned int* gas_ptr;
typedef __attribute__((address_space(3))) unsigned int* las_ptr;
__device__ __forceinline__ void lds_load16(const void* g, void* l) {
    __builtin_amdgcn_global_load_lds((gas_ptr)g, (las_ptr)l, 16, 0, 0);
}

__device__ __forceinline__ void split_f8(float4 a, float4 b, short8& hi, short8& lo) {
    float f[8] = {a.x, a.y, a.z, a.w, b.x, b.y, b.z, b.w};
#pragma unroll
    for (int i = 0; i < 8; ++i) {
        unsigned short h = f2bf(f[i]);
        hi[i] = (short)h;
        lo[i] = (short)f2bf(f[i] - bf2f(h));
    }
}

__device__ __forceinline__ float4 f4add(float4 a, float4 b) {
    return make_float4(a.x + b.x, a.y + b.y, a.z + b.z, a.w + b.w);
}

// accumulate a bf16x4 row fragment into a float4
__device__ __forceinline__ void accum_bf4(float4& a, ushort4 v) {
    a.x += bf2f(v.x); a.y += bf2f(v.y); a.z += bf2f(v.z); a.w += bf2f(v.w);
}

// ---------------- preprocessing: degree, CSR build ----------------

__global__ void zero_kernel(int* counts, int* fillpos, int n) {
    int i = blockIdx.x * 256 + threadIdx.x;
    if (i < n) { counts[i] = 0; fillpos[i] = 0; }
}

__global__ void hist_kernel(const int* __restrict__ dst, int* __restrict__ counts, int E) {
    int e = blockIdx.x * 256 + threadIdx.x;
    if (e < E) atomicAdd(&counts[dst[e]], 1);
}

__global__ void scan_block_kernel(const int* __restrict__ counts, int* __restrict__ row_ptr,
                                  int* __restrict__ blocksums, int n) {
    __shared__ int s[256];
    int tid = threadIdx.x;
    int i = blockIdx.x * 256 + tid;
    int v = (i < n) ? counts[i] : 0;
    s[tid] = v; __syncthreads();
    for (int off = 1; off < 256; off <<= 1) {
        int t = (tid >= off) ? s[tid - off] : 0;
        __syncthreads();
        s[tid] += t;
        __syncthreads();
    }
    if (i < n) row_ptr[i] = s[tid] - v;
    if (tid == 255) blocksums[blockIdx.x] = s[255];
}

__global__ void scan_sums_kernel(const int* __restrict__ blocksums, int* __restrict__ blockoffs, int nb) {
    __shared__ int s[256];
    int tid = threadIdx.x;
    int v = (tid < nb) ? blocksums[tid] : 0;
    s[tid] = v; __syncthreads();
    for (int off = 1; off < 256; off <<= 1) {
        int t = (tid >= off) ? s[tid - off] : 0;
        __syncthreads();
        s[tid] += t;
        __syncthreads();
    }
    blockoffs[tid] = s[tid] - v;
}

__global__ void finalize_rowptr_kernel(int* __restrict__ row_ptr, const int* __restrict__ blockoffs,
                                       const int* __restrict__ counts, float* __restrict__ inv_sqrt,
                                       int n, int E) {
    int i = blockIdx.x * 256 + threadIdx.x;
    if (i < n) {
        row_ptr[i] += blockoffs[i >> 8];
        inv_sqrt[i] = rsqrtf((float)(counts[i] + 1));
    }
    if (i == 0) row_ptr[n] = E;
}

__global__ void fill_kernel(const int* __restrict__ src, const int* __restrict__ dst,
                            const int* __restrict__ row_ptr, int* __restrict__ fillpos,
                            int* __restrict__ src_sorted, int E) {
    int e = blockIdx.x * 256 + threadIdx.x;
    if (e < E) {
        int d = dst[e];
        int pos = row_ptr[d] + atomicAdd(&fillpos[d], 1);
        src_sorted[pos] = src[e];
    }
}

// ---------------- weight split+transpose: W[K][Ncol] fp32 -> Wt_hi/lo [Ncol][K] bf16 ----------------

__global__ void cvt_w_kernel(const float* __restrict__ W, unsigned short* __restrict__ hi,
                             unsigned short* __restrict__ lo, int K, int Ncol) {
    int idx = blockIdx.x * 256 + threadIdx.x;
    if (idx >= K * Ncol) return;
    int k = idx / Ncol, n = idx % Ncol;
    float f = W[idx];
    unsigned short h = f2bf(f);
    hi[(size_t)n * K + k] = h;
    lo[(size_t)n * K + k] = f2bf(f - bf2f(h));
}

// ---------------- split-bf16 MFMA GEMM ----------------
// C[row][col] = bf16( (A @ W)[row][col] * inv_sqrt[row] ), A = Ahi+Alo, W = Whi+Wlo (3 MFMAs)
// 128x128 tile, BK=32, 4 waves, each wave 64x64 = 4x4 frags of 16x16x32.
// LDS fragment-linear per 16-row block: elem(m^,k_local) at 8*m^ + 128*(k_local>>3) + (k_local&7)
//   => a frag read is lane*16B contiguous (ds_read_b128, conflict-free).
// Wt is [n][k] so B-fragments are contiguous 16B runs too.

template<bool A_SPLIT>
__global__ __launch_bounds__(256) void gemm_mfma_kernel(
        const float* __restrict__ Afp,
        const unsigned short* __restrict__ gAhi, const unsigned short* __restrict__ gAlo,
        const unsigned short* __restrict__ Wthi, const unsigned short* __restrict__ Wtlo,
        const float* __restrict__ inv_sqrt, unsigned short* __restrict__ C,
        int M, int K, int Ncol) {
    __shared__ unsigned short AhiL[4096], AloL[4096], BhiL[4096], BloL[4096];
    const int tid  = threadIdx.x;
    const int lane = tid & 63;
    const int w    = tid >> 6;        // wave 0..3
    const int wr   = w >> 1, wc = w & 1;
    const int lm   = lane & 15;
    const int lk8  = (lane >> 4) * 8;
    const int bm   = blockIdx.x * 128;
    const int bn   = blockIdx.y * 128;

    f32x4v acc[4][4] = {};

    // --- B staging pointers (wave fills n-blocks 2w, 2w+1, hi+lo) ---
    int nc0 = bn + 16 * (2 * w) + lm;
    int nc1 = bn + 16 * (2 * w + 1) + lm;
    const unsigned short* gB_h0 = Wthi + (size_t)nc0 * K + lk8;
    const unsigned short* gB_h1 = Wthi + (size_t)nc1 * K + lk8;
    const unsigned short* gB_l0 = Wtlo + (size_t)nc0 * K + lk8;
    const unsigned short* gB_l1 = Wtlo + (size_t)nc1 * K + lk8;

    // --- A staging pointers ---
    // A_SPLIT: wave fills m-blocks 2w, 2w+1 via global_load_lds (lane i -> ushort i*8)
    int ar0 = bm + 16 * (2 * w) + lm;     if (ar0 >= M) ar0 = M - 1;
    int ar1 = bm + 16 * (2 * w + 1) + lm; if (ar1 >= M) ar1 = M - 1;
    const unsigned short* gA_h0 = gAhi ? gAhi + (size_t)ar0 * K + lk8 : nullptr;
    const unsigned short* gA_h1 = gAhi ? gAhi + (size_t)ar1 * K + lk8 : nullptr;
    const unsigned short* gA_l0 = gAlo ? gAlo + (size_t)ar0 * K + lk8 : nullptr;
    const unsigned short* gA_l1 = gAlo ? gAlo + (size_t)ar1 * K + lk8 : nullptr;

    // !A_SPLIT: thread converts 16 fp32 of its row: block cb, lane-in-block cs.
    // k segments {cs>>4, (cs>>4)+2}. LDS offsets: 8*cs (= 128*(cs>>4)+8*(cs&15)) and +256.
    const int cb = tid >> 5;
    const int cs = tid & 31;
    int crow = bm + 16 * cb + (cs & 15); if (crow >= M) crow = M - 1;
    const int ck = (cs >> 4) * 8;
    const float* Abase = Afp ? Afp + (size_t)crow * K + ck : nullptr;
    unsigned short* ldsA_hi = &AhiL[cb * 512 + 8 * cs];
    unsigned short* ldsA_lo = &AloL[cb * 512 + 8 * cs];

    for (int k0 = 0; k0 < K; k0 += 32) {
        // ---- stage A ----
        if (A_SPLIT) {
            lds_load16(gA_h0 + k0, &AhiL[(2 * w) * 512]);
            lds_load16(gA_h1 + k0, &AhiL[(2 * w + 1) * 512]);
            lds_load16(gA_l0 + k0, &AloL[(2 * w) * 512]);
            lds_load16(gA_l1 + k0, &AloL[(2 * w + 1) * 512]);
        } else {
            float4 a0 = *(const float4*)(Abase + k0);
            float4 a1 = *(const float4*)(Abase + k0 + 4);
            float4 c0 = *(const float4*)(Abase + k0 + 16);
            float4 c1 = *(const float4*)(Abase + k0 + 20);
            short8 h0, l0, h1, l1;
            split_f8(a0, a1, h0, l0);
            split_f8(c0, c1, h1, l1);
            *(short8*)ldsA_hi         = h0;
            *(short8*)(ldsA_hi + 256) = h1;
            *(short8*)ldsA_lo         = l0;
            *(short8*)(ldsA_lo + 256) = l1;
        }
        // ---- stage B ----
        lds_load16(gB_h0 + k0, &BhiL[(2 * w) * 512]);
        lds_load16(gB_h1 + k0, &BhiL[(2 * w + 1) * 512]);
        lds_load16(gB_l0 + k0, &BloL[(2 * w) * 512]);
        lds_load16(gB_l1 + k0, &BloL[(2 * w + 1) * 512]);
        __syncthreads();

        // ---- fragments ----
        short8 ah[4], av[4], bh[4], bv[4];
#pragma unroll
        for (int i = 0; i < 4; ++i) {
            int ao = (wr * 4 + i) * 512 + lane * 8;
            int bo = (wc * 4 + i) * 512 + lane * 8;
            ah[i] = *(const short8*)&AhiL[ao];
            av[i] = *(const short8*)&AloL[ao];
            bh[i] = *(const short8*)&BhiL[bo];
            bv[i] = *(const short8*)&BloL[bo];
        }
#pragma unroll
        for (int i = 0; i < 4; ++i)
#pragma unroll
            for (int j = 0; j < 4; ++j) {
                acc[i][j] = __builtin_amdgcn_mfma_f32_16x16x32_bf16(ah[i], bh[j], acc[i][j], 0, 0, 0);
                acc[i][j] = __builtin_amdgcn_mfma_f32_16x16x32_bf16(av[i], bh[j], acc[i][j], 0, 0, 0);
                acc[i][j] = __builtin_amdgcn_mfma_f32_16x16x32_bf16(ah[i], bv[j], acc[i][j], 0, 0, 0);
            }
        __syncthreads();
    }

    // ---- epilogue: C/D layout col=lane&15, row=(lane>>4)*4+r ; store bf16 ----
    const int orow_base = bm + wr * 64;
    const int ocol_base = bn + wc * 64 + lm;
    const int rq = (lane >> 4) * 4;
#pragma unroll
    for (int i = 0; i < 4; ++i) {
#pragma unroll
        for (int r = 0; r < 4; ++r) {
            int row = orow_base + i * 16 + rq + r;
            if (row >= M) continue;
            float s = inv_sqrt[row];
            size_t rb = (size_t)row * Ncol;
#pragma unroll
            for (int j = 0; j < 4; ++j)
                C[rb + ocol_base + j * 16] = f2bf(acc[i][j][r] * s);
        }
    }
}

// ---------------- fp32 vector GEMM for layer 3 (A given as hi/lo bf16) ----------------

__global__ __launch_bounds__(256) void gemm_scaled_hl_kernel(
        const unsigned short* __restrict__ Ahi, const unsigned short* __restrict__ Alo,
        const float* __restrict__ W,
        const float* __restrict__ inv_sqrt, float* __restrict__ C,
        int M, int K, int Ncol) {
    __shared__ float As[16][64];
    __shared__ float Ws[16][64];
    int tid = threadIdx.x;
    int tm = tid >> 4;
    int tn = tid & 15;
    int bm = blockIdx.x * 64;
    int bn = blockIdx.y * 64;

    float acc[4][4] = {};

    int lr = tid >> 2;
    int lc = (tid & 3) << 2;
    int wr = tid >> 4;
    int wc = (tid & 15) << 2;
    int arow = bm + lr;
    bool aok = arow < M;
    bool wok = (bn + wc) < Ncol;
    const unsigned short* AhiRow = Ahi + (size_t)arow * K + lc;
    const unsigned short* AloRow = Alo + (size_t)arow * K + lc;

    for (int k0 = 0; k0 < K; k0 += 16) {
        float4 av = make_float4(0.f, 0.f, 0.f, 0.f);
        if (aok) {
            ushort4 hv = *(const ushort4*)(AhiRow + k0);
            ushort4 lv = *(const ushort4*)(AloRow + k0);
            av.x = bf2f(hv.x) + bf2f(lv.x);
            av.y = bf2f(hv.y) + bf2f(lv.y);
            av.z = bf2f(hv.z) + bf2f(lv.z);
            av.w = bf2f(hv.w) + bf2f(lv.w);
        }
        As[lc + 0][lr] = av.x; As[lc + 1][lr] = av.y;
        As[lc + 2][lr] = av.z; As[lc + 3][lr] = av.w;

        float4 wv = make_float4(0.f, 0.f, 0.f, 0.f);
        if (wok) wv = *(const float4*)(W + (size_t)(k0 + wr) * Ncol + bn + wc);
        *(float4*)&Ws[wr][wc] = wv;
        __syncthreads();

#pragma unroll
        for (int k = 0; k < 16; ++k) {
            const float4 a4 = *(const float4*)&As[k][tm << 2];
            const float4 b4 = *(const float4*)&Ws[k][tn << 2];
            float a[4] = {a4.x, a4.y, a4.z, a4.w};
            float b[4] = {b4.x, b4.y, b4.z, b4.w};
#pragma unroll
            for (int i = 0; i < 4; ++i)
#pragma unroll
                for (int j = 0; j < 4; ++j)
                    acc[i][j] = fmaf(a[i], b[j], acc[i][j]);
        }
        __syncthreads();
    }

#pragma unroll
    for (int i = 0; i < 4; ++i) {
        int row = bm + (tm << 2) + i;
        if (row >= M) continue;
        float s = inv_sqrt[row];
        int col = bn + (tn << 2);
        if (col < Ncol) {
            float4 o = make_float4(acc[i][0] * s, acc[i][1] * s, acc[i][2] * s, acc[i][3] * s);
            *(float4*)&C[(size_t)row * Ncol + col] = o;
        }
    }
}

// ---------------- aggregation (H=256): one wave per node; g is bf16, acc fp32 ----------------
// Indices batch-loaded 64/wave + __shfl broadcast; gathers unrolled 8-wide.

__global__ __launch_bounds__(256) void agg_bn_hl_kernel(
        const unsigned short* __restrict__ g, const int* __restrict__ row_ptr,
        const int* __restrict__ srcs, const float* __restrict__ inv_sqrt,
        const float* __restrict__ bias, const float* __restrict__ gamma,
        const float* __restrict__ beta, const float* __restrict__ mean,
        const float* __restrict__ var,
        unsigned short* __restrict__ out_hi, unsigned short* __restrict__ out_lo, int n) {
    int node = (blockIdx.x << 2) + (threadIdx.x >> 6);
    int lane = threadIdx.x & 63;
    if (node >= n) return;
    const ushort4* gp = (const ushort4*)g;   // 64 ushort4 per 256-elem row
    float4 acc0 = make_float4(0.f, 0.f, 0.f, 0.f);
    float4 acc1 = make_float4(0.f, 0.f, 0.f, 0.f);
    accum_bf4(acc0, gp[(size_t)node * 64 + lane]);   // self-loop
    int beg = row_ptr[node];
    int cnt = row_ptr[node + 1] - beg;

    for (int base = 0; base < cnt; base += 64) {
        int m = cnt - base; if (m > 64) m = 64;
        int idx = (lane < m) ? srcs[beg + base + lane] : 0;
        int j = 0;
        for (; j + 8 <= m; j += 8) {
            int s0 = __shfl(idx, j + 0), s1 = __shfl(idx, j + 1);
            int s2 = __shfl(idx, j + 2), s3 = __shfl(idx, j + 3);
            int s4 = __shfl(idx, j + 4), s5 = __shfl(idx, j + 5);
            int s6 = __shfl(idx, j + 6), s7 = __shfl(idx, j + 7);
            ushort4 v0 = gp[(size_t)s0 * 64 + lane];
            ushort4 v1 = gp[(size_t)s1 * 64 + lane];
            ushort4 v2 = gp[(size_t)s2 * 64 + lane];
            ushort4 v3 = gp[(size_t)s3 * 64 + lane];
            ushort4 v4 = gp[(size_t)s4 * 64 + lane];
            ushort4 v5 = gp[(size_t)s5 * 64 + lane];
            ushort4 v6 = gp[(size_t)s6 * 64 + lane];
            ushort4 v7 = gp[(size_t)s7 * 64 + lane];
            accum_bf4(acc0, v0); accum_bf4(acc0, v1);
            accum_bf4(acc0, v2); accum_bf4(acc0, v3);
            accum_bf4(acc1, v4); accum_bf4(acc1, v5);
            accum_bf4(acc1, v6); accum_bf4(acc1, v7);
        }
        for (; j < m; ++j) {
            int s = __shfl(idx, j);
            accum_bf4(acc0, gp[(size_t)s * 64 + lane]);
        }
    }
    float4 acc = f4add(acc0, acc1);

    float inv = inv_sqrt[node];
    float4 b4  = ((const float4*)bias)[lane];
    float4 ga4 = ((const float4*)gamma)[lane];
    float4 be4 = ((const float4*)beta)[lane];
    float4 m4  = ((const float4*)mean)[lane];
    float4 v4  = ((const float4*)var)[lane];
    float4 o;
    o.x = fmaxf((acc.x * inv + b4.x - m4.x) * (ga4.x * rsqrtf(v4.x + EPS)) + be4.x, 0.f);
    o.y = fmaxf((acc.y * inv + b4.y - m4.y) * (ga4.y * rsqrtf(v4.y + EPS)) + be4.y, 0.f);
    o.z = fmaxf((acc.z * inv + b4.z - m4.z) * (ga4.z * rsqrtf(v4.z + EPS)) + be4.z, 0.f);
    o.w = fmaxf((acc.w * inv + b4.w - m4.w) * (ga4.w * rsqrtf(v4.w + EPS)) + be4.w, 0.f);
    ushort4 oh, ol;
    oh.x = f2bf(o.x); ol.x = f2bf(o.x - bf2f(oh.x));
    oh.y = f2bf(o.y); ol.y = f2bf(o.y - bf2f(oh.y));
    oh.z = f2bf(o.z); ol.z = f2bf(o.z - bf2f(oh.z));
    oh.w = f2bf(o.w); ol.w = f2bf(o.w - bf2f(oh.w));
    ((ushort4*)out_hi)[(size_t)node * 64 + lane] = oh;
    ((ushort4*)out_lo)[(size_t)node * 64 + lane] = ol;
}

// ---------------- final aggregation (C=40): fp32; all 64 lanes stay alive for shfl ----------------

__global__ __launch_bounds__(256) void agg_final_kernel(
        const float* __restrict__ g, const int* __restrict__ row_ptr,
        const int* __restrict__ srcs, const float* __restrict__ inv_sqrt,
        const float* __restrict__ bias, float* __restrict__ out, int n) {
    int node = (blockIdx.x << 2) + (threadIdx.x >> 6);
    int lane = threadIdx.x & 63;
    if (node >= n) return;
    int flane = (lane < CLS) ? lane : 0;       // clamped gather lane; store masked below
    float acc0 = g[(size_t)node * CLS + flane];
    float acc1 = 0.f;
    int beg = row_ptr[node];
    int cnt = row_ptr[node + 1] - beg;

    for (int base = 0; base < cnt; base += 64) {
        int m = cnt - base; if (m > 64) m = 64;
        int idx = (lane < m) ? srcs[beg + base + lane] : 0;
        int j = 0;
        for (; j + 8 <= m; j += 8) {
            int s0 = __shfl(idx, j + 0), s1 = __shfl(idx, j + 1);
            int s2 = __shfl(idx, j + 2), s3 = __shfl(idx, j + 3);
            int s4 = __shfl(idx, j + 4), s5 = __shfl(idx, j + 5);
            int s6 = __shfl(idx, j + 6), s7 = __shfl(idx, j + 7);
            float v0 = g[(size_t)s0 * CLS + flane];
            float v1 = g[(size_t)s1 * CLS + flane];
            float v2 = g[(size_t)s2 * CLS + flane];
            float v3 = g[(size_t)s3 * CLS + flane];
            float v4 = g[(size_t)s4 * CLS + flane];
            float v5 = g[(size_t)s5 * CLS + flane];
            float v6 = g[(size_t)s6 * CLS + flane];
            float v7 = g[(size_t)s7 * CLS + flane];
            acc0 += (v0 + v1) + (v2 + v3);
            acc1 += (v4 + v5) + (v6 + v7);
        }
        for (; j < m; ++j) {
            int s = __shfl(idx, j);
            acc0 += g[(size_t)s * CLS + flane];
        }
    }
    if (lane < CLS)
        out[(size_t)node * CLS + lane] = (acc0 + acc1) * inv_sqrt[node] + bias[lane];
}

// ---------------- launch ----------------

extern "C" void kernel_launch(void* const* d_in, const int* in_sizes, int n_in,
                              void* d_out, int out_size, void* d_ws, size_t ws_size,
                              hipStream_t stream) {
    const float* x     = (const float*)d_in[0];
    const int*   edges = (const int*)d_in[1];
    const float* W1    = (const float*)d_in[2];
    const float* b1    = (const float*)d_in[3];
    const float* W2    = (const float*)d_in[4];
    const float* b2    = (const float*)d_in[5];
    const float* W3    = (const float*)d_in[6];
    const float* b3    = (const float*)d_in[7];
    const float* gamma = (const float*)d_in[8];
    const float* beta  = (const float*)d_in[9];
    const float* mean  = (const float*)d_in[10];
    const float* var   = (const float*)d_in[11];

    const int N = in_sizes[0] / FEAT;   // 50000
    const int E = in_sizes[1] / 2;      // 800000
    const int* src = edges;
    const int* dst = edges + E;

    char* ws = (char*)d_ws;
    auto alloc = [&](size_t bytes) -> char* {
        char* p = ws;
        ws += (bytes + 255) & ~(size_t)255;
        return p;
    };
    int*   counts     = (int*)  alloc((size_t)N * 4);
    int*   fillpos    = (int*)  alloc((size_t)N * 4);
    int*   row_ptr    = (int*)  alloc((size_t)(N + 1) * 4);
    int*   blocksums  = (int*)  alloc(256 * 4);
    int*   blockoffs  = (int*)  alloc(256 * 4);
    float* inv_sqrt   = (float*)alloc((size_t)N * 4);
    int*   src_sorted = (int*)  alloc((size_t)E * 4);
    unsigned short* w1hi = (unsigned short*)alloc((size_t)FEAT * HID * 2);
    unsigned short* w1lo = (unsigned short*)alloc((size_t)FEAT * HID * 2);
    unsigned short* w2hi = (unsigned short*)alloc((size_t)HID * HID * 2);
    unsigned short* w2lo = (unsigned short*)alloc((size_t)HID * HID * 2);
    // g: bf16 for layers 1-2 (25.6 MB); reused as fp32 N*CLS (8 MB) for layer 3
    unsigned short* g    = (unsigned short*)alloc((size_t)N * HID * 2);
    unsigned short* h_hi = (unsigned short*)alloc((size_t)N * HID * 2); // 25.6 MB
    unsigned short* h_lo = (unsigned short*)alloc((size_t)N * HID * 2); // 25.6 MB

    int nb = (N + 255) / 256;
    int eb = (E + 255) / 256;

    zero_kernel<<<nb, 256, 0, stream>>>(counts, fillpos, N);
    hist_kernel<<<eb, 256, 0, stream>>>(dst, counts, E);
    scan_block_kernel<<<nb, 256, 0, stream>>>(counts, row_ptr, blocksums, N);
    scan_sums_kernel<<<1, 256, 0, stream>>>(blocksums, blockoffs, nb);
    finalize_rowptr_kernel<<<nb, 256, 0, stream>>>(row_ptr, blockoffs, counts, inv_sqrt, N, E);
    fill_kernel<<<eb, 256, 0, stream>>>(src, dst, row_ptr, fillpos, src_sorted, E);

    cvt_w_kernel<<<(FEAT * HID + 255) / 256, 256, 0, stream>>>(W1, w1hi, w1lo, FEAT, HID);
    cvt_w_kernel<<<(HID * HID + 255) / 256, 256, 0, stream>>>(W2, w2hi, w2lo, HID, HID);

    dim3 mfma_grid((N + 127) / 128, HID / 128);
    dim3 gemm3_grid((N + 63) / 64, 1);
    dim3 agg_grid((N + 3) / 4);

    // layer 1: A = x fp32 (on-the-fly split); output g bf16
    gemm_mfma_kernel<false><<<mfma_grid, 256, 0, stream>>>(
        x, nullptr, nullptr, w1hi, w1lo, inv_sqrt, g, N, FEAT, HID);
    agg_bn_hl_kernel<<<agg_grid, 256, 0, stream>>>(g, row_ptr, src_sorted, inv_sqrt,
                                                   b1, gamma, beta, mean, var, h_hi, h_lo, N);
    // layer 2: A = h1 (pre-split hi/lo); output g bf16
    gemm_mfma_kernel<true><<<mfma_grid, 256, 0, stream>>>(
        nullptr, h_hi, h_lo, w2hi, w2lo, inv_sqrt, g, N, HID, HID);
    agg_bn_hl_kernel<<<agg_grid, 256, 0, stream>>>(g, row_ptr, src_sorted, inv_sqrt,
                                                   b2, gamma, beta, mean, var, h_hi, h_lo, N);
    // layer 3: fp32 vector GEMM reading hi/lo; fp32 g3 (reuses g buffer); fp32 final agg
    float* g3 = (float*)g;
    gemm_scaled_hl_kernel<<<gemm3_grid, 256, 0, stream>>>(h_hi, h_lo, W3, inv_sqrt, g3, N, HID, CLS);
    agg_final_kernel<<<agg_grid, 256, 0, stream>>>(g3, row_ptr, src_sorted, inv_sqrt,
                                                   b3, (float*)d_out, N);
}